// Round 10
// baseline (226.832 us; speedup 1.0000x reference)
//
#include <hip/hip_runtime.h>

#define Bb 2
#define Ss 2048
#define Dd 1024
#define Hh 16
#define HDd 64
#define BS (Bb * Ss)

typedef __attribute__((ext_vector_type(8))) __bf16 bf16x8;
typedef __attribute__((ext_vector_type(8))) unsigned short u16x8;
typedef __attribute__((ext_vector_type(4))) float f32x4;

__device__ __forceinline__ unsigned short f2bf(float f) {
  union { float f; unsigned u; } v; v.f = f;
  unsigned r = v.u + 0x7fffu + ((v.u >> 16) & 1u);
  return (unsigned short)(r >> 16);
}
__device__ __forceinline__ unsigned short f2bf_fast(float f) {  // RN, no tie fix
  union { float f; unsigned u; } v; v.f = f;
  return (unsigned short)((v.u + 0x8000u) >> 16);
}

// async global->LDS, 16B per lane; LDS dest = wave-uniform base + lane*16.
// R8 lesson: keep <=4 in flight per thread (8 outstanding raced on replay).
__device__ __forceinline__ void gl_lds16(const void* g, void* l) {
  __builtin_amdgcn_global_load_lds(
      (const __attribute__((address_space(1))) void*)g,
      (__attribute__((address_space(3))) void*)l, 16, 0, 0);
}

// -------- cast fp32 -> bf16 (x, wq|wk|wv stacked, wo) + RoPE cos/sin table --
__global__ __launch_bounds__(256) void cast_all(
    const float4* __restrict__ x, const float4* __restrict__ wq,
    const float4* __restrict__ wk, const float4* __restrict__ wv,
    const float4* __restrict__ wo, ushort4* __restrict__ xb,
    ushort4* __restrict__ wqkvb, ushort4* __restrict__ wob,
    float* __restrict__ ct, float* __restrict__ st) {
  int i = blockIdx.x * 256 + threadIdx.x;
  const int NX4 = BS * Dd / 4;   // 1M
  const int NW4 = Dd * Dd / 4;   // 256K
  const float4* src;
  ushort4* dst;
  int idx;
  if (i < NX4) { src = x; dst = xb; idx = i; }
  else if ((i -= NX4) < NW4) { src = wq; dst = wqkvb; idx = i; }
  else if ((i -= NW4) < NW4) { src = wk; dst = wqkvb + NW4; idx = i; }
  else if ((i -= NW4) < NW4) { src = wv; dst = wqkvb + 2 * NW4; idx = i; }
  else if ((i -= NW4) < NW4) { src = wo; dst = wob; idx = i; }
  else if ((i -= NW4) < Ss * 32) {  // RoPE table: i = s*32 + j
    int s = i >> 5, jj = i & 31;
    float freq = __powf(10000.0f, -(float)jj * (1.0f / 32.0f));
    float cs, sn;
    sincosf((float)s * freq, &sn, &cs);
    ct[i] = cs; st[i] = sn;
    return;
  } else return;
  float4 v = src[idx];
  ushort4 o;
  o.x = f2bf(v.x); o.y = f2bf(v.y); o.z = f2bf(v.z); o.w = f2bf(v.w);
  dst[idx] = o;
}

// -------- fused QKV GEMM + QK-RMSNorm + RoPE + layout -----------------------
// R17: single-buffer BK=32 (dbuf regressed twice: R9, R16). bounds(256,3).
__global__ __launch_bounds__(256, 3) void gemm_qkv(
    const unsigned short* __restrict__ A, const unsigned short* __restrict__ Bw,
    const float* __restrict__ qw, const float* __restrict__ kw,
    const float* __restrict__ ct, const float* __restrict__ st,
    unsigned short* __restrict__ Qb, unsigned short* __restrict__ Kb,
    unsigned short* __restrict__ Vt) {
  __shared__ __align__(16) unsigned short As[128 * 32];
  __shared__ __align__(16) unsigned short Bs[128 * 32];
  const int K = Dd, tid = threadIdx.x;
  const int lane = tid & 63;
  const int quad = lane >> 4;
  const int l16 = lane & 15;
  const int wave = tid >> 6;
  const int wm = (wave >> 1) * 64;
  const int wn = (wave & 1) * 64;
  const int tile_m = blockIdx.y * 128;
  const int tile_n = blockIdx.x * 128;

  const int off0 = tid * 16;
  const int off1 = 4096 + tid * 16;
  const int r0 = tid >> 2, r1 = r0 + 64;
  const int sch = (((tid & 3) ^ ((tid >> 3) & 3)) << 3);  // swizzled src elem
  const int xg = ((quad ^ ((l16 >> 1) & 3)) << 3);        // swizzled read elem

  const unsigned short* Ag0 = A + (size_t)(tile_m + r0) * K + sch;
  const unsigned short* Ag1 = A + (size_t)(tile_m + r1) * K + sch;
  const unsigned short* Bg0 = Bw + (size_t)(tile_n + r0) * K + sch;
  const unsigned short* Bg1 = Bw + (size_t)(tile_n + r1) * K + sch;

  f32x4 zero = {0.f, 0.f, 0.f, 0.f};
  f32x4 acc[4][4];
#pragma unroll
  for (int mi = 0; mi < 4; ++mi)
#pragma unroll
    for (int ni = 0; ni < 4; ++ni) acc[mi][ni] = zero;

  for (int k0 = 0; k0 < K; k0 += 32) {
    gl_lds16(Ag0 + k0, (char*)As + off0);
    gl_lds16(Ag1 + k0, (char*)As + off1);
    gl_lds16(Bg0 + k0, (char*)Bs + off0);
    gl_lds16(Bg1 + k0, (char*)Bs + off1);
    __syncthreads();
    bf16x8 af[4], bfv[4];
#pragma unroll
    for (int mi = 0; mi < 4; ++mi)
      af[mi] = *(const bf16x8*)&As[(wm + mi * 16 + l16) * 32 + xg];
#pragma unroll
    for (int ni = 0; ni < 4; ++ni)
      bfv[ni] = *(const bf16x8*)&Bs[(wn + ni * 16 + l16) * 32 + xg];
#pragma unroll
    for (int mi = 0; mi < 4; ++mi)
#pragma unroll
      for (int ni = 0; ni < 4; ++ni)
        acc[mi][ni] = __builtin_amdgcn_mfma_f32_16x16x32_bf16(
            af[mi], bfv[ni], acc[mi][ni], 0, 0, 0);
    __syncthreads();
  }

  // ---- fused epilogue. C-layout: row = wm+mi*16+quad*4+r, col = wn+ni*16+l16
  const int type = blockIdx.x >> 3;                    // 0=Q,1=K,2=V
  const int h = (((blockIdx.x & 7) << 7) + wn) >> 6;   // head index
  const int bb = tile_m >> 11;
  const size_t bh = (size_t)bb * Hh + h;

  if (type == 2) {  // V: transpose store Vt[bh][d][s], pack 4 tokens
#pragma unroll
    for (int mi = 0; mi < 4; ++mi) {
      int s0 = (tile_m + wm + mi * 16 + quad * 4) & (Ss - 1);
#pragma unroll
      for (int ni = 0; ni < 4; ++ni) {
        int d = ni * 16 + l16;
        ushort4 pv;
        pv.x = f2bf(acc[mi][ni][0]);
        pv.y = f2bf(acc[mi][ni][1]);
        pv.z = f2bf(acc[mi][ni][2]);
        pv.w = f2bf(acc[mi][ni][3]);
        *(ushort4*)&Vt[(bh * HDd + d) * Ss + s0] = pv;
      }
    }
  } else {
    const float* wnp = type ? kw : qw;
    unsigned short* Ob = type ? Kb : Qb;
    // Q folds softmax scale and log2(e): flash then uses raw exp2.
    const float fscale = type ? 1.0f : 0.125f * 1.44269504f;
    float w0[4];
#pragma unroll
    for (int ni = 0; ni < 4; ++ni) w0[ni] = wnp[ni * 16 + l16];
#pragma unroll
    for (int mi = 0; mi < 4; ++mi) {
#pragma unroll
      for (int r = 0; r < 4; ++r) {
        int s = (tile_m + wm + mi * 16 + quad * 4 + r) & (Ss - 1);
        float ss2 = 0.f;
#pragma unroll
        for (int ni = 0; ni < 4; ++ni) ss2 += acc[mi][ni][r] * acc[mi][ni][r];
        ss2 += __shfl_xor(ss2, 1, 64);
        ss2 += __shfl_xor(ss2, 2, 64);
        ss2 += __shfl_xor(ss2, 4, 64);
        ss2 += __shfl_xor(ss2, 8, 64);
        float rr = rsqrtf(ss2 * (1.0f / 64.0f) + 1e-6f) * fscale;
        float c0 = ct[s * 32 + l16], c1 = ct[s * 32 + 16 + l16];
        float sn0 = st[s * 32 + l16], sn1 = st[s * 32 + 16 + l16];
#pragma unroll
        for (int ni = 0; ni < 4; ++ni) {
          float vn = acc[mi][ni][r] * rr * w0[ni];
          float vp = acc[mi][ni ^ 2][r] * rr * w0[ni ^ 2];
          float cs_ = (ni & 1) ? c1 : c0;
          float sn_ = (ni & 1) ? sn1 : sn0;
          float sg = (ni < 2) ? -1.0f : 1.0f;
          Ob[(bh * Ss + s) * HDd + ni * 16 + l16] = f2bf(vn * cs_ + sg * vp * sn_);
        }
      }
    }
  }
}

// -------- bf16 GEMM 128x64 tile, 2-phase dbuf (R16 config RESTORED) ---------
// R20 post-mortem: 128^2 at 256 WGs = 1 WG/CU regressed (-3.5us total) —
// latency-bound with no TLP. 128x64 @ 512 WGs = 2/CU was the win; keep it.
__global__ __launch_bounds__(256) void gemm_bt2(
    const unsigned short* __restrict__ A, const unsigned short* __restrict__ Bw,
    float* __restrict__ C, int M, int N, int K) {
  __shared__ __align__(16) unsigned short As[2][128 * 32];
  __shared__ __align__(16) unsigned short Bs[2][64 * 32];
  const int tid = threadIdx.x;
  const int lane = tid & 63;
  const int quad = lane >> 4;
  const int l16 = lane & 15;
  const int wave = tid >> 6;
  const int wm = (wave >> 1) * 64;
  const int wn = (wave & 1) * 32;
  const int tile_m = blockIdx.y * 128;
  const int tile_n = blockIdx.x * 64;

  const int off0 = tid * 16;
  const int off1 = 4096 + tid * 16;
  const int r0 = tid >> 2, r1 = r0 + 64;
  const int sch = (((tid & 3) ^ ((tid >> 3) & 3)) << 3);
  const int xg = ((quad ^ ((l16 >> 1) & 3)) << 3);

  const unsigned short* Ag0 = A + (size_t)(tile_m + r0) * K + sch;
  const unsigned short* Ag1 = A + (size_t)(tile_m + r1) * K + sch;
  const unsigned short* Bg0 = Bw + (size_t)(tile_n + r0) * K + sch;

  f32x4 zero = {0.f, 0.f, 0.f, 0.f};
  f32x4 acc[4][2];
#pragma unroll
  for (int mi = 0; mi < 4; ++mi)
#pragma unroll
    for (int ni = 0; ni < 2; ++ni) acc[mi][ni] = zero;

  gl_lds16(Ag0, (char*)As[0] + off0);
  gl_lds16(Ag1, (char*)As[0] + off1);
  gl_lds16(Bg0, (char*)Bs[0] + off0);
  __syncthreads();

  int cur = 0;
  for (int k0 = 0; k0 < K; k0 += 32, cur ^= 1) {
    if (k0 + 32 < K) {
      gl_lds16(Ag0 + k0 + 32, (char*)As[cur ^ 1] + off0);
      gl_lds16(Ag1 + k0 + 32, (char*)As[cur ^ 1] + off1);
      gl_lds16(Bg0 + k0 + 32, (char*)Bs[cur ^ 1] + off0);
    }
    bf16x8 af[4], bfv[2];
#pragma unroll
    for (int mi = 0; mi < 4; ++mi)
      af[mi] = *(const bf16x8*)&As[cur][(wm + mi * 16 + l16) * 32 + xg];
#pragma unroll
    for (int ni = 0; ni < 2; ++ni)
      bfv[ni] = *(const bf16x8*)&Bs[cur][(wn + ni * 16 + l16) * 32 + xg];
#pragma unroll
    for (int mi = 0; mi < 4; ++mi)
#pragma unroll
      for (int ni = 0; ni < 2; ++ni)
        acc[mi][ni] = __builtin_amdgcn_mfma_f32_16x16x32_bf16(
            af[mi], bfv[ni], acc[mi][ni], 0, 0, 0);
    __syncthreads();
  }

#pragma unroll
  for (int mi = 0; mi < 4; ++mi) {
#pragma unroll
    for (int ni = 0; ni < 2; ++ni) {
      int col = tile_n + wn + ni * 16 + l16;
#pragma unroll
      for (int r = 0; r < 4; ++r) {
        int row = tile_m + wm + mi * 16 + quad * 4 + r;
        C[(size_t)row * N + col] = acc[mi][ni][r];
      }
    }
  }
}

// -------- flash attention R21: K fragments direct from global (L2-hot) ------
// R19/R18 evidence: flash is LDS-read-throughput-bound (occupancy-insensitive
// 12.5->22.6% at 43us; ~22 b128-class LDS ops/wave-iter, 8 of them K-frags).
// Key: the K-frag pattern K[kv=ni*16+l16][d=quad*8..] is EXACTLY the proven
// Q direct-load pattern, and K tiles are L2-pinned (R14: bh==lid%8 -> 2MB/XCD,
// FETCH 97->12MB). So read K straight from global:
//  * deletes K LDS staging (2 gl_lds/iter) + 8 ds_read_b128/wave-iter (22->14);
//  * LDS 40960 -> 24576 B (Vs 16K + Ps 8K) -> bounds(256,6), VGPR cap 85;
//    grid 1024 lands 4 WGs/CU everywhere, more occupancy headroom;
//  * barrier now only guards V staging (kt>0); V stays LDS-staged (transpose
//    layout); R19 constant-sum qt map + XCD bh-pin kept.
__global__ __launch_bounds__(256, 6) void flash(
    const unsigned short* __restrict__ Qb, const unsigned short* __restrict__ Kb,
    const unsigned short* __restrict__ Vt, const float* __restrict__ sink,
    unsigned short* __restrict__ Ob) {
  __shared__ __align__(16) unsigned short Vs[2][64 * 64];   // V^T tile [d][kv]
  __shared__ __align__(16) unsigned short Ps[4][16 * 64];   // XOR-swizzled

  int tid = threadIdx.x, lane = tid & 63, wave = tid >> 6;
  int quad = lane >> 4, l16 = lane & 15;

  int lid = blockIdx.x;             // 0..1023
  int u = lid >> 8, v = lid & 255;
  int w = (v >> 5) & 7;
  int bh = ((v >> 3) & 3) * 8 + (v & 7);  // XCD pin: bh === lid (mod 8)
  int qt = (u == 0) ? 2 * w : (u == 1) ? 31 - 2 * w
         : (u == 2) ? 2 * w + 1 : 30 - 2 * w;
  int b = bh >> 4, h = bh & 15;

  const unsigned short* Qg = Qb + ((size_t)(b * Hh + h) * Ss) * HDd;
  const unsigned short* Kg = Kb + ((size_t)(b * Hh + h) * Ss) * HDd;
  const unsigned short* Vg = Vt + ((size_t)(b * Hh + h) * HDd) * Ss;

  int off0 = tid * 16, off1 = 4096 + tid * 16;
  int sr0 = tid >> 3, sr1 = sr0 + 32;
  int sch = ((tid & 7) ^ (sr0 & 7)) * 8;   // XOR-swizzled source chunk
  int x0 = ((quad ^ (l16 & 7)) * 8);       // swizzled read offset (V)
  int x1 = x0 ^ 32;

  int q0 = qt * 64;
  int myq = q0 + wave * 16 + l16;   // this lane's query

  float sk = sink[h];
  f32x4 zero = {0.f, 0.f, 0.f, 0.f};

  bf16x8 ones;  // all-ones A-frag for l row-sum MFMA
  {
    u16x8 tt;
#pragma unroll
    for (int i = 0; i < 8; ++i) tt[i] = 0x3F80;  // bf16 1.0
    ones = *(bf16x8*)&tt;
  }

  // Q fragments: direct global->reg
  const unsigned short* Qrow = Qg + (size_t)myq * HDd;
  bf16x8 aq0 = *(const bf16x8*)(Qrow + quad * 8);
  bf16x8 aq1 = *(const bf16x8*)(Qrow + 32 + quad * 8);

  // V tile 0 -> LDS
  gl_lds16(Vg + (size_t)sr0 * Ss + sch, (char*)Vs[0] + off0);
  gl_lds16(Vg + (size_t)sr1 * Ss + sch, (char*)Vs[0] + off1);

  f32x4 Oacc[4], lacc = zero;
#pragma unroll
  for (int ni = 0; ni < 4; ++ni) Oacc[ni] = zero;

  // QK for kt=0: K fragments direct from global (same pattern as Q)
  f32x4 sc[4];
#pragma unroll
  for (int ni = 0; ni < 4; ++ni) {
    const unsigned short* Krow = Kg + (size_t)(ni * 16 + l16) * HDd;
    bf16x8 bk0 = *(const bf16x8*)(Krow + quad * 8);
    bf16x8 bk1 = *(const bf16x8*)(Krow + 32 + quad * 8);
    sc[ni] = __builtin_amdgcn_mfma_f32_16x16x32_bf16(bk0, aq0, zero, 0, 0, 0);
    sc[ni] = __builtin_amdgcn_mfma_f32_16x16x32_bf16(bk1, aq1, sc[ni], 0, 0, 0);
  }
  if (qt == 0) {
#pragma unroll
    for (int ni = 0; ni < 4; ++ni)
#pragma unroll
      for (int r = 0; r < 4; ++r)
        if (ni * 16 + quad * 4 + r > myq - q0) sc[ni][r] = -1.0e38f;
  }

  __syncthreads();  // V0 staged

  char* Pw = (char*)Ps[wave];
  const int prow = l16 * 128;
  const int psw = l16 & 7;

  for (int kt = 0; kt <= qt; ++kt) {
    bool last = (kt == qt);
    if (kt > 0) __syncthreads();  // drains V[kt]; WAR-safe for V[kt+1] buffer
    if (kt + 1 <= qt) {  // V prefetch depth 1 (PV[kt+1] runs next iteration)
      gl_lds16(Vg + (size_t)sr0 * Ss + (kt + 1) * 64 + sch, (char*)Vs[(kt + 1) & 1] + off0);
      gl_lds16(Vg + (size_t)sr1 * Ss + (kt + 1) * 64 + sch, (char*)Vs[(kt + 1) & 1] + off1);
    }

    // p = exp2(sc[kt]); pack & write P (VALU overlaps load latency)
#pragma unroll
    for (int ni = 0; ni < 4; ++ni) {
      ushort4 pk;
      pk.x = f2bf_fast(exp2f(sc[ni][0]));
      pk.y = f2bf_fast(exp2f(sc[ni][1]));
      pk.z = f2bf_fast(exp2f(sc[ni][2]));
      pk.w = f2bf_fast(exp2f(sc[ni][3]));
      int chunk = (ni * 2 + (quad >> 1)) ^ psw;
      *(ushort4*)(Pw + prow + chunk * 16 + (quad & 1) * 8) = pk;
    }

    // QK for kt+1 (pipelined above PV[kt]); K frags direct from global
    __builtin_amdgcn_s_setprio(1);
    f32x4 scn[4];
    if (!last) {
#pragma unroll
      for (int ni = 0; ni < 4; ++ni) {
        const unsigned short* Krow =
            Kg + (size_t)((kt + 1) * 64 + ni * 16 + l16) * HDd;
        bf16x8 bk0 = *(const bf16x8*)(Krow + quad * 8);
        bf16x8 bk1 = *(const bf16x8*)(Krow + 32 + quad * 8);
        scn[ni] = __builtin_amdgcn_mfma_f32_16x16x32_bf16(bk0, aq0, zero, 0, 0, 0);
        scn[ni] = __builtin_amdgcn_mfma_f32_16x16x32_bf16(bk1, aq1, scn[ni], 0, 0, 0);
      }
      if (kt + 1 == qt) {  // diagonal mask for next tile
#pragma unroll
        for (int ni = 0; ni < 4; ++ni)
#pragma unroll
          for (int r = 0; r < 4; ++r)
            if ((kt + 1) * 64 + ni * 16 + quad * 4 + r > myq) scn[ni][r] = -1.0e38f;
      }
    }

    asm volatile("s_waitcnt lgkmcnt(0)" ::: "memory");  // P visible in-wave
    bf16x8 ap0 = *(const bf16x8*)(Pw + prow + ((quad ^ psw) * 16));
    bf16x8 ap1 = *(const bf16x8*)(Pw + prow + (((quad + 4) ^ psw) * 16));

    // O^T[d][q] += V^T·P^T ; l row-sum via ones-frag MFMA
    const unsigned short* Vtile = Vs[kt & 1];
#pragma unroll
    for (int ni = 0; ni < 4; ++ni) {
      bf16x8 bv0 = *(const bf16x8*)&Vtile[(ni * 16 + l16) * 64 + x0];
      bf16x8 bv1 = *(const bf16x8*)&Vtile[(ni * 16 + l16) * 64 + x1];
      Oacc[ni] = __builtin_amdgcn_mfma_f32_16x16x32_bf16(bv0, ap0, Oacc[ni], 0, 0, 0);
      Oacc[ni] = __builtin_amdgcn_mfma_f32_16x16x32_bf16(bv1, ap1, Oacc[ni], 0, 0, 0);
    }
    lacc = __builtin_amdgcn_mfma_f32_16x16x32_bf16(ones, ap0, lacc, 0, 0, 0);
    lacc = __builtin_amdgcn_mfma_f32_16x16x32_bf16(ones, ap1, lacc, 0, 0, 0);
    __builtin_amdgcn_s_setprio(0);

    if (!last) {
#pragma unroll
      for (int ni = 0; ni < 4; ++ni) sc[ni] = scn[ni];
    }
  }

  // epilogue: every lane already holds l(q=myq) in lacc[0]
  float inv = 1.0f / (lacc[0] + exp2f(sk * 1.44269504f));
#pragma unroll
  for (int ni = 0; ni < 4; ++ni) {
    ushort4 ov;
    ov.x = f2bf(Oacc[ni][0] * inv);
    ov.y = f2bf(Oacc[ni][1] * inv);
    ov.z = f2bf(Oacc[ni][2] * inv);
    ov.w = f2bf(Oacc[ni][3] * inv);
    *(ushort4*)&Ob[((size_t)b * Ss + myq) * Dd + h * 64 + ni * 16 + quad * 4] = ov;
  }
}

extern "C" void kernel_launch(void* const* d_in, const int* in_sizes, int n_in,
                              void* d_out, int out_size, void* d_ws, size_t ws_size,
                              hipStream_t stream) {
  const float* x  = (const float*)d_in[0];
  const float* wq = (const float*)d_in[1];
  const float* wk = (const float*)d_in[2];
  const float* wv = (const float*)d_in[3];
  const float* wo = (const float*)d_in[4];
  const float* qw = (const float*)d_in[5];
  const float* kw = (const float*)d_in[6];
  const float* sk = (const float*)d_in[7];

  char* ws = (char*)d_ws;
  const size_t MB = 1ull << 20;
  unsigned short* xb    = (unsigned short*)(ws + 0);       // 8 MB (dead after gemm_qkv)
  unsigned short* attnb = (unsigned short*)(ws + 0);       // 8 MB (after flash)
  unsigned short* wqkvb = (unsigned short*)(ws + 8 * MB);  // 6 MB
  unsigned short* wob   = (unsigned short*)(ws + 14 * MB); // 2 MB
  float*          ct    = (float*)(ws + 16 * MB);          // 256 KB
  float*          st    = (float*)(ws + 17 * MB);          // 256 KB
  unsigned short* Qb    = (unsigned short*)(ws + 40 * MB); // 8 MB
  unsigned short* Kb    = (unsigned short*)(ws + 48 * MB); // 8 MB
  unsigned short* Vt    = (unsigned short*)(ws + 56 * MB); // 8 MB

  cast_all<<<8448, 256, 0, stream>>>(
      (const float4*)x, (const float4*)wq, (const float4*)wk, (const float4*)wv,
      (const float4*)wo, (ushort4*)xb, (ushort4*)wqkvb, (ushort4*)wob, ct, st);
  gemm_qkv<<<dim3(24, 32), 256, 0, stream>>>(xb, wqkvb, qw, kw, ct, st, Qb, Kb, Vt);
  flash<<<dim3(1024), 256, 0, stream>>>(Qb, Kb, Vt, sk, attnb);
  gemm_bt2<<<dim3(16, 32), 256, 0, stream>>>(attnb, wob, (float*)d_out, BS, Dd, Dd);
}

// Round 11
// 179.372 us; speedup vs baseline: 1.2646x; 1.2646x over previous
//
#include <hip/hip_runtime.h>

#define Bb 2
#define Ss 2048
#define Dd 1024
#define Hh 16
#define HDd 64
#define BS (Bb * Ss)

typedef __attribute__((ext_vector_type(8))) __bf16 bf16x8;
typedef __attribute__((ext_vector_type(8))) unsigned short u16x8;
typedef __attribute__((ext_vector_type(4))) float f32x4;

__device__ __forceinline__ unsigned short f2bf(float f) {
  union { float f; unsigned u; } v; v.f = f;
  unsigned r = v.u + 0x7fffu + ((v.u >> 16) & 1u);
  return (unsigned short)(r >> 16);
}
__device__ __forceinline__ unsigned short f2bf_fast(float f) {  // RN, no tie fix
  union { float f; unsigned u; } v; v.f = f;
  return (unsigned short)((v.u + 0x8000u) >> 16);
}

// async global->LDS, 16B per lane; LDS dest = wave-uniform base + lane*16.
// R8 lesson: keep <=4 in flight per thread (8 outstanding raced on replay).
// R21 lesson: K frags MUST stay LDS-staged — direct-from-global scatters 64
// L2 transactions per fragment (flash 43->88us). LDS converts that to one
// coalesced fetch + broadcast reads.
__device__ __forceinline__ void gl_lds16(const void* g, void* l) {
  __builtin_amdgcn_global_load_lds(
      (const __attribute__((address_space(1))) void*)g,
      (__attribute__((address_space(3))) void*)l, 16, 0, 0);
}

// -------- cast fp32 -> bf16 (x, wq|wk|wv stacked, wo) + RoPE cos/sin table --
__global__ __launch_bounds__(256) void cast_all(
    const float4* __restrict__ x, const float4* __restrict__ wq,
    const float4* __restrict__ wk, const float4* __restrict__ wv,
    const float4* __restrict__ wo, ushort4* __restrict__ xb,
    ushort4* __restrict__ wqkvb, ushort4* __restrict__ wob,
    float* __restrict__ ct, float* __restrict__ st) {
  int i = blockIdx.x * 256 + threadIdx.x;
  const int NX4 = BS * Dd / 4;   // 1M
  const int NW4 = Dd * Dd / 4;   // 256K
  const float4* src;
  ushort4* dst;
  int idx;
  if (i < NX4) { src = x; dst = xb; idx = i; }
  else if ((i -= NX4) < NW4) { src = wq; dst = wqkvb; idx = i; }
  else if ((i -= NW4) < NW4) { src = wk; dst = wqkvb + NW4; idx = i; }
  else if ((i -= NW4) < NW4) { src = wv; dst = wqkvb + 2 * NW4; idx = i; }
  else if ((i -= NW4) < NW4) { src = wo; dst = wob; idx = i; }
  else if ((i -= NW4) < Ss * 32) {  // RoPE table: i = s*32 + j
    int s = i >> 5, jj = i & 31;
    float freq = __powf(10000.0f, -(float)jj * (1.0f / 32.0f));
    float cs, sn;
    sincosf((float)s * freq, &sn, &cs);
    ct[i] = cs; st[i] = sn;
    return;
  } else return;
  float4 v = src[idx];
  ushort4 o;
  o.x = f2bf(v.x); o.y = f2bf(v.y); o.z = f2bf(v.z); o.w = f2bf(v.w);
  dst[idx] = o;
}

// -------- fused QKV GEMM + QK-RMSNorm + RoPE + layout -----------------------
// R17 (best measured): single-buffer BK=32 (dbuf regressed twice: R9, R16).
__global__ __launch_bounds__(256, 3) void gemm_qkv(
    const unsigned short* __restrict__ A, const unsigned short* __restrict__ Bw,
    const float* __restrict__ qw, const float* __restrict__ kw,
    const float* __restrict__ ct, const float* __restrict__ st,
    unsigned short* __restrict__ Qb, unsigned short* __restrict__ Kb,
    unsigned short* __restrict__ Vt) {
  __shared__ __align__(16) unsigned short As[128 * 32];
  __shared__ __align__(16) unsigned short Bs[128 * 32];
  const int K = Dd, tid = threadIdx.x;
  const int lane = tid & 63;
  const int quad = lane >> 4;
  const int l16 = lane & 15;
  const int wave = tid >> 6;
  const int wm = (wave >> 1) * 64;
  const int wn = (wave & 1) * 64;
  const int tile_m = blockIdx.y * 128;
  const int tile_n = blockIdx.x * 128;

  const int off0 = tid * 16;
  const int off1 = 4096 + tid * 16;
  const int r0 = tid >> 2, r1 = r0 + 64;
  const int sch = (((tid & 3) ^ ((tid >> 3) & 3)) << 3);  // swizzled src elem
  const int xg = ((quad ^ ((l16 >> 1) & 3)) << 3);        // swizzled read elem

  const unsigned short* Ag0 = A + (size_t)(tile_m + r0) * K + sch;
  const unsigned short* Ag1 = A + (size_t)(tile_m + r1) * K + sch;
  const unsigned short* Bg0 = Bw + (size_t)(tile_n + r0) * K + sch;
  const unsigned short* Bg1 = Bw + (size_t)(tile_n + r1) * K + sch;

  f32x4 zero = {0.f, 0.f, 0.f, 0.f};
  f32x4 acc[4][4];
#pragma unroll
  for (int mi = 0; mi < 4; ++mi)
#pragma unroll
    for (int ni = 0; ni < 4; ++ni) acc[mi][ni] = zero;

  for (int k0 = 0; k0 < K; k0 += 32) {
    gl_lds16(Ag0 + k0, (char*)As + off0);
    gl_lds16(Ag1 + k0, (char*)As + off1);
    gl_lds16(Bg0 + k0, (char*)Bs + off0);
    gl_lds16(Bg1 + k0, (char*)Bs + off1);
    __syncthreads();
    bf16x8 af[4], bfv[4];
#pragma unroll
    for (int mi = 0; mi < 4; ++mi)
      af[mi] = *(const bf16x8*)&As[(wm + mi * 16 + l16) * 32 + xg];
#pragma unroll
    for (int ni = 0; ni < 4; ++ni)
      bfv[ni] = *(const bf16x8*)&Bs[(wn + ni * 16 + l16) * 32 + xg];
#pragma unroll
    for (int mi = 0; mi < 4; ++mi)
#pragma unroll
      for (int ni = 0; ni < 4; ++ni)
        acc[mi][ni] = __builtin_amdgcn_mfma_f32_16x16x32_bf16(
            af[mi], bfv[ni], acc[mi][ni], 0, 0, 0);
    __syncthreads();
  }

  // ---- fused epilogue. C-layout: row = wm+mi*16+quad*4+r, col = wn+ni*16+l16
  const int type = blockIdx.x >> 3;                    // 0=Q,1=K,2=V
  const int h = (((blockIdx.x & 7) << 7) + wn) >> 6;   // head index
  const int bb = tile_m >> 11;
  const size_t bh = (size_t)bb * Hh + h;

  if (type == 2) {  // V: transpose store Vt[bh][d][s], pack 4 tokens
#pragma unroll
    for (int mi = 0; mi < 4; ++mi) {
      int s0 = (tile_m + wm + mi * 16 + quad * 4) & (Ss - 1);
#pragma unroll
      for (int ni = 0; ni < 4; ++ni) {
        int d = ni * 16 + l16;
        ushort4 pv;
        pv.x = f2bf(acc[mi][ni][0]);
        pv.y = f2bf(acc[mi][ni][1]);
        pv.z = f2bf(acc[mi][ni][2]);
        pv.w = f2bf(acc[mi][ni][3]);
        *(ushort4*)&Vt[(bh * HDd + d) * Ss + s0] = pv;
      }
    }
  } else {
    const float* wnp = type ? kw : qw;
    unsigned short* Ob = type ? Kb : Qb;
    // Q folds softmax scale and log2(e): flash then uses raw exp2.
    const float fscale = type ? 1.0f : 0.125f * 1.44269504f;
    float w0[4];
#pragma unroll
    for (int ni = 0; ni < 4; ++ni) w0[ni] = wnp[ni * 16 + l16];
#pragma unroll
    for (int mi = 0; mi < 4; ++mi) {
#pragma unroll
      for (int r = 0; r < 4; ++r) {
        int s = (tile_m + wm + mi * 16 + quad * 4 + r) & (Ss - 1);
        float ss2 = 0.f;
#pragma unroll
        for (int ni = 0; ni < 4; ++ni) ss2 += acc[mi][ni][r] * acc[mi][ni][r];
        ss2 += __shfl_xor(ss2, 1, 64);
        ss2 += __shfl_xor(ss2, 2, 64);
        ss2 += __shfl_xor(ss2, 4, 64);
        ss2 += __shfl_xor(ss2, 8, 64);
        float rr = rsqrtf(ss2 * (1.0f / 64.0f) + 1e-6f) * fscale;
        float c0 = ct[s * 32 + l16], c1 = ct[s * 32 + 16 + l16];
        float sn0 = st[s * 32 + l16], sn1 = st[s * 32 + 16 + l16];
#pragma unroll
        for (int ni = 0; ni < 4; ++ni) {
          float vn = acc[mi][ni][r] * rr * w0[ni];
          float vp = acc[mi][ni ^ 2][r] * rr * w0[ni ^ 2];
          float cs_ = (ni & 1) ? c1 : c0;
          float sn_ = (ni & 1) ? sn1 : sn0;
          float sg = (ni < 2) ? -1.0f : 1.0f;
          Ob[(bh * Ss + s) * HDd + ni * 16 + l16] = f2bf(vn * cs_ + sg * vp * sn_);
        }
      }
    }
  }
}

// -------- bf16 GEMM 128x64 tile, 2-phase dbuf (R16 config, best measured) ---
// R20 post-mortem: 128^2 @ 1 WG/CU regressed (no TLP). 128x64 @ 512 WGs kept.
__global__ __launch_bounds__(256) void gemm_bt2(
    const unsigned short* __restrict__ A, const unsigned short* __restrict__ Bw,
    float* __restrict__ C, int M, int N, int K) {
  __shared__ __align__(16) unsigned short As[2][128 * 32];
  __shared__ __align__(16) unsigned short Bs[2][64 * 32];
  const int tid = threadIdx.x;
  const int lane = tid & 63;
  const int quad = lane >> 4;
  const int l16 = lane & 15;
  const int wave = tid >> 6;
  const int wm = (wave >> 1) * 64;
  const int wn = (wave & 1) * 32;
  const int tile_m = blockIdx.y * 128;
  const int tile_n = blockIdx.x * 64;

  const int off0 = tid * 16;
  const int off1 = 4096 + tid * 16;
  const int r0 = tid >> 2, r1 = r0 + 64;
  const int sch = (((tid & 3) ^ ((tid >> 3) & 3)) << 3);
  const int xg = ((quad ^ ((l16 >> 1) & 3)) << 3);

  const unsigned short* Ag0 = A + (size_t)(tile_m + r0) * K + sch;
  const unsigned short* Ag1 = A + (size_t)(tile_m + r1) * K + sch;
  const unsigned short* Bg0 = Bw + (size_t)(tile_n + r0) * K + sch;

  f32x4 zero = {0.f, 0.f, 0.f, 0.f};
  f32x4 acc[4][2];
#pragma unroll
  for (int mi = 0; mi < 4; ++mi)
#pragma unroll
    for (int ni = 0; ni < 2; ++ni) acc[mi][ni] = zero;

  gl_lds16(Ag0, (char*)As[0] + off0);
  gl_lds16(Ag1, (char*)As[0] + off1);
  gl_lds16(Bg0, (char*)Bs[0] + off0);
  __syncthreads();

  int cur = 0;
  for (int k0 = 0; k0 < K; k0 += 32, cur ^= 1) {
    if (k0 + 32 < K) {
      gl_lds16(Ag0 + k0 + 32, (char*)As[cur ^ 1] + off0);
      gl_lds16(Ag1 + k0 + 32, (char*)As[cur ^ 1] + off1);
      gl_lds16(Bg0 + k0 + 32, (char*)Bs[cur ^ 1] + off0);
    }
    bf16x8 af[4], bfv[2];
#pragma unroll
    for (int mi = 0; mi < 4; ++mi)
      af[mi] = *(const bf16x8*)&As[cur][(wm + mi * 16 + l16) * 32 + xg];
#pragma unroll
    for (int ni = 0; ni < 2; ++ni)
      bfv[ni] = *(const bf16x8*)&Bs[cur][(wn + ni * 16 + l16) * 32 + xg];
#pragma unroll
    for (int mi = 0; mi < 4; ++mi)
#pragma unroll
      for (int ni = 0; ni < 2; ++ni)
        acc[mi][ni] = __builtin_amdgcn_mfma_f32_16x16x32_bf16(
            af[mi], bfv[ni], acc[mi][ni], 0, 0, 0);
    __syncthreads();
  }

#pragma unroll
  for (int mi = 0; mi < 4; ++mi) {
#pragma unroll
    for (int ni = 0; ni < 2; ++ni) {
      int col = tile_n + wn + ni * 16 + l16;
#pragma unroll
      for (int r = 0; r < 4; ++r) {
        int row = tile_m + wm + mi * 16 + quad * 4 + r;
        C[(size_t)row * N + col] = acc[mi][ni][r];
      }
    }
  }
}

// -------- flash attention R15 (best measured; restored verbatim) ------------
// Final flash model (R12-R21 evidence): latency/LDS-throughput-bound at
// ~43us. Not memory-bound (FETCH 12MB), not occupancy-bound (12.5->22.6% at
// constant time), K must stay LDS-staged (R21: global-K = 2x worse). The
// remaining lever is a 32x32-MFMA 32q/wave restructure (halves LDS traffic
// per q-row) — deferred as high-risk.
__global__ __launch_bounds__(256, 3) void flash(
    const unsigned short* __restrict__ Qb, const unsigned short* __restrict__ Kb,
    const unsigned short* __restrict__ Vt, const float* __restrict__ sink,
    unsigned short* __restrict__ Ob) {
  __shared__ __align__(16) unsigned short Ks[2][64 * 64];
  __shared__ __align__(16) unsigned short Vs[2][64 * 64];   // V^T tile [d][kv]
  __shared__ __align__(16) unsigned short Ps[4][16 * 64];   // XOR-swizzled

  int tid = threadIdx.x, lane = tid & 63, wave = tid >> 6;
  int quad = lane >> 4, l16 = lane & 15;

  int lid = blockIdx.x;             // 0..1023, longest-first
  int qt = 31 - (lid >> 5);
  int bh = 8 * ((lid >> 3) & 3) + (lid & 7);
  int b = bh >> 4, h = bh & 15;

  const unsigned short* Qg = Qb + ((size_t)(b * Hh + h) * Ss) * HDd;
  const unsigned short* Kg = Kb + ((size_t)(b * Hh + h) * Ss) * HDd;
  const unsigned short* Vg = Vt + ((size_t)(b * Hh + h) * HDd) * Ss;

  int off0 = tid * 16, off1 = 4096 + tid * 16;
  int sr0 = tid >> 3, sr1 = sr0 + 32;
  int sch = ((tid & 7) ^ (sr0 & 7)) * 8;   // XOR-swizzled source chunk
  int x0 = ((quad ^ (l16 & 7)) * 8);       // swizzled read offset
  int x1 = x0 ^ 32;

  int q0 = qt * 64;
  int myq = q0 + wave * 16 + l16;   // this lane's query

  float sk = sink[h];
  f32x4 zero = {0.f, 0.f, 0.f, 0.f};

  bf16x8 ones;  // all-ones A-frag for l row-sum MFMA
  {
    u16x8 tt;
#pragma unroll
    for (int i = 0; i < 8; ++i) tt[i] = 0x3F80;  // bf16 1.0
    ones = *(bf16x8*)&tt;
  }

  // Q fragments: direct global->reg (no LDS round trip)
  const unsigned short* Qrow = Qg + (size_t)myq * HDd;
  bf16x8 aq0 = *(const bf16x8*)(Qrow + quad * 8);
  bf16x8 aq1 = *(const bf16x8*)(Qrow + 32 + quad * 8);

  gl_lds16(Kg + (size_t)sr0 * 64 + sch, (char*)Ks[0] + off0);
  gl_lds16(Kg + (size_t)sr1 * 64 + sch, (char*)Ks[0] + off1);
  gl_lds16(Vg + (size_t)sr0 * Ss + sch, (char*)Vs[0] + off0);
  gl_lds16(Vg + (size_t)sr1 * Ss + sch, (char*)Vs[0] + off1);

  f32x4 Oacc[4], lacc = zero;
#pragma unroll
  for (int ni = 0; ni < 4; ++ni) Oacc[ni] = zero;

  __syncthreads();  // K0, V0 staged (drains Q reg loads too)
  if (qt >= 1) {    // prefetch K tile 1 (read during kt=0's pipelined QK[1])
    gl_lds16(Kg + (size_t)(64 + sr0) * 64 + sch, (char*)Ks[1] + off0);
    gl_lds16(Kg + (size_t)(64 + sr1) * 64 + sch, (char*)Ks[1] + off1);
  }

  // QK for kt=0
  f32x4 sc[4];
#pragma unroll
  for (int ni = 0; ni < 4; ++ni) {
    bf16x8 bk0 = *(const bf16x8*)&Ks[0][(ni * 16 + l16) * 64 + x0];
    bf16x8 bk1 = *(const bf16x8*)&Ks[0][(ni * 16 + l16) * 64 + x1];
    sc[ni] = __builtin_amdgcn_mfma_f32_16x16x32_bf16(bk0, aq0, zero, 0, 0, 0);
    sc[ni] = __builtin_amdgcn_mfma_f32_16x16x32_bf16(bk1, aq1, sc[ni], 0, 0, 0);
  }
  if (qt == 0) {
#pragma unroll
    for (int ni = 0; ni < 4; ++ni)
#pragma unroll
      for (int r = 0; r < 4; ++r)
        if (ni * 16 + quad * 4 + r > myq - q0) sc[ni][r] = -1.0e38f;
  }

  char* Pw = (char*)Ps[wave];
  const int prow = l16 * 128;
  const int psw = l16 & 7;

  for (int kt = 0; kt <= qt; ++kt) {
    bool last = (kt == qt);
    // barrier at top of EVERY iteration: drains K[kt+1] (needed this iter)
    // and V[kt] (needed this iter; V[qt] is why last also barriers).
    if (qt > 0) __syncthreads();
    if (kt + 2 <= qt) {  // K prefetch depth 2 (QK[kt+1] runs this iteration)
      gl_lds16(Kg + (size_t)((kt + 2) * 64 + sr0) * 64 + sch, (char*)Ks[kt & 1] + off0);
      gl_lds16(Kg + (size_t)((kt + 2) * 64 + sr1) * 64 + sch, (char*)Ks[kt & 1] + off1);
    }
    if (kt + 1 <= qt) {  // V prefetch depth 1 (PV[kt+1] runs next iteration)
      gl_lds16(Vg + (size_t)sr0 * Ss + (kt + 1) * 64 + sch, (char*)Vs[(kt + 1) & 1] + off0);
      gl_lds16(Vg + (size_t)sr1 * Ss + (kt + 1) * 64 + sch, (char*)Vs[(kt + 1) & 1] + off1);
    }

    // p = exp2(sc[kt]); pack & write P (VALU overlaps next K-frag latency)
#pragma unroll
    for (int ni = 0; ni < 4; ++ni) {
      ushort4 pk;
      pk.x = f2bf_fast(exp2f(sc[ni][0]));
      pk.y = f2bf_fast(exp2f(sc[ni][1]));
      pk.z = f2bf_fast(exp2f(sc[ni][2]));
      pk.w = f2bf_fast(exp2f(sc[ni][3]));
      int chunk = (ni * 2 + (quad >> 1)) ^ psw;
      *(ushort4*)(Pw + prow + chunk * 16 + (quad & 1) * 8) = pk;
    }

    // QK for kt+1 (pipelined above PV[kt]) — high prio: keep matrix pipe fed
    __builtin_amdgcn_s_setprio(1);
    f32x4 scn[4];
    if (!last) {
      const unsigned short* Kt = Ks[(kt + 1) & 1];
#pragma unroll
      for (int ni = 0; ni < 4; ++ni) {
        bf16x8 bk0 = *(const bf16x8*)&Kt[(ni * 16 + l16) * 64 + x0];
        bf16x8 bk1 = *(const bf16x8*)&Kt[(ni * 16 + l16) * 64 + x1];
        scn[ni] = __builtin_amdgcn_mfma_f32_16x16x32_bf16(bk0, aq0, zero, 0, 0, 0);
        scn[ni] = __builtin_amdgcn_mfma_f32_16x16x32_bf16(bk1, aq1, scn[ni], 0, 0, 0);
      }
      if (kt + 1 == qt) {  // diagonal mask for next tile
#pragma unroll
        for (int ni = 0; ni < 4; ++ni)
#pragma unroll
          for (int r = 0; r < 4; ++r)
            if ((kt + 1) * 64 + ni * 16 + quad * 4 + r > myq) scn[ni][r] = -1.0e38f;
      }
    }

    asm volatile("s_waitcnt lgkmcnt(0)" ::: "memory");  // P visible in-wave
    bf16x8 ap0 = *(const bf16x8*)(Pw + prow + ((quad ^ psw) * 16));
    bf16x8 ap1 = *(const bf16x8*)(Pw + prow + (((quad + 4) ^ psw) * 16));

    // O^T[d][q] += V^T·P^T ; l row-sum via ones-frag MFMA
    const unsigned short* Vtile = Vs[kt & 1];
#pragma unroll
    for (int ni = 0; ni < 4; ++ni) {
      bf16x8 bv0 = *(const bf16x8*)&Vtile[(ni * 16 + l16) * 64 + x0];
      bf16x8 bv1 = *(const bf16x8*)&Vtile[(ni * 16 + l16) * 64 + x1];
      Oacc[ni] = __builtin_amdgcn_mfma_f32_16x16x32_bf16(bv0, ap0, Oacc[ni], 0, 0, 0);
      Oacc[ni] = __builtin_amdgcn_mfma_f32_16x16x32_bf16(bv1, ap1, Oacc[ni], 0, 0, 0);
    }
    lacc = __builtin_amdgcn_mfma_f32_16x16x32_bf16(ones, ap0, lacc, 0, 0, 0);
    lacc = __builtin_amdgcn_mfma_f32_16x16x32_bf16(ones, ap1, lacc, 0, 0, 0);
    __builtin_amdgcn_s_setprio(0);

    if (!last) {
#pragma unroll
      for (int ni = 0; ni < 4; ++ni) sc[ni] = scn[ni];
    }
  }

  // epilogue: every lane already holds l(q=myq) in lacc[0]
  float inv = 1.0f / (lacc[0] + exp2f(sk * 1.44269504f));
#pragma unroll
  for (int ni = 0; ni < 4; ++ni) {
    ushort4 ov;
    ov.x = f2bf(Oacc[ni][0] * inv);
    ov.y = f2bf(Oacc[ni][1] * inv);
    ov.z = f2bf(Oacc[ni][2] * inv);
    ov.w = f2bf(Oacc[ni][3] * inv);
    *(ushort4*)&Ob[((size_t)b * Ss + myq) * Dd + h * 64 + ni * 16 + quad * 4] = ov;
  }
}

extern "C" void kernel_launch(void* const* d_in, const int* in_sizes, int n_in,
                              void* d_out, int out_size, void* d_ws, size_t ws_size,
                              hipStream_t stream) {
  const float* x  = (const float*)d_in[0];
  const float* wq = (const float*)d_in[1];
  const float* wk = (const float*)d_in[2];
  const float* wv = (const float*)d_in[3];
  const float* wo = (const float*)d_in[4];
  const float* qw = (const float*)d_in[5];
  const float* kw = (const float*)d_in[6];
  const float* sk = (const float*)d_in[7];

  char* ws = (char*)d_ws;
  const size_t MB = 1ull << 20;
  unsigned short* xb    = (unsigned short*)(ws + 0);       // 8 MB (dead after gemm_qkv)
  unsigned short* attnb = (unsigned short*)(ws + 0);       // 8 MB (after flash)
  unsigned short* wqkvb = (unsigned short*)(ws + 8 * MB);  // 6 MB
  unsigned short* wob   = (unsigned short*)(ws + 14 * MB); // 2 MB
  float*          ct    = (float*)(ws + 16 * MB);          // 256 KB
  float*          st    = (float*)(ws + 17 * MB);          // 256 KB
  unsigned short* Qb    = (unsigned short*)(ws + 40 * MB); // 8 MB
  unsigned short* Kb    = (unsigned short*)(ws + 48 * MB); // 8 MB
  unsigned short* Vt    = (unsigned short*)(ws + 56 * MB); // 8 MB

  cast_all<<<8448, 256, 0, stream>>>(
      (const float4*)x, (const float4*)wq, (const float4*)wk, (const float4*)wv,
      (const float4*)wo, (ushort4*)xb, (ushort4*)wqkvb, (ushort4*)wob, ct, st);
  gemm_qkv<<<dim3(24, 32), 256, 0, stream>>>(xb, wqkvb, qw, kw, ct, st, Qb, Kb, Vt);
  flash<<<dim3(1024), 256, 0, stream>>>(Qb, Kb, Vt, sk, attnb);
  gemm_bt2<<<dim3(16, 32), 256, 0, stream>>>(attnb, wob, (float*)d_out, BS, Dd, Dd);
}